// Round 18
// baseline (337.988 us; speedup 1.0000x reference)
//
#include <hip/hip_runtime.h>
#include <cstdint>
#include <cstddef>

#define DEV __device__ __forceinline__

typedef unsigned short u16;
typedef unsigned int u32;
typedef __attribute__((ext_vector_type(8))) short s16x8;   // 8 x bf16 (raw bits)
typedef __attribute__((ext_vector_type(4))) float f32x4;
typedef __attribute__((ext_vector_type(4))) unsigned int u32x4;
typedef __attribute__((ext_vector_type(2))) unsigned int u32x2;

typedef unsigned int u32_as1 __attribute__((address_space(1)));
typedef unsigned int u32_as3 __attribute__((address_space(3)));

DEV u16 f2bf(float f){
  unsigned u = __float_as_uint(f);
  u += 0x7fffu + ((u >> 16) & 1u);   // RNE
  return (u16)(u >> 16);
}

DEV float bf2f(u16 v){ return __uint_as_float(((u32)v) << 16); }

DEV u32 cvtpk_bf16(float lo, float hi){
  u32 r;
  asm("v_cvt_pk_bf16_f32 %0, %1, %2" : "=v"(r) : "v"(lo), "v"(hi));
  return r;
}

DEV float fexp2(float x){            // 2^x, single v_exp_f32
  float r;
  asm("v_exp_f32 %0, %1" : "=v"(r) : "v"(x));
  return r;
}

DEV float frcp(float x){             // 1/x, single v_rcp_f32 (1 ulp)
  float r;
  asm("v_rcp_f32 %0, %1" : "=v"(r) : "v"(x));
  return r;
}

DEV void gload16(const void* g, void* l){
  // async global->LDS, 16B per lane; LDS dest = wave-uniform base + lane*16
  __builtin_amdgcn_global_load_lds((const u32_as1*)g, (u32_as3*)l, 16, 0, 0);
}

// tanh-GELU via one exp2: x * t/(t+1), t = exp2(2.3022083*(x + 0.044715 x^3)).
// |err vs erf-GELU| < 4e-4. z clamped to 100 so t never overflows to inf.
DEV float gelu_tanh(float x){
  float x2 = x*x;
  float z = 2.3022083f * x * fmaf(x2, 0.044715f, 1.0f);
  z = fminf(z, 100.0f);
  float t = fexp2(z);
  return x * t * frcp(t + 1.0f);
}

// ---------- weight transpose+convert: W[K][N] f32 -> Wt[N][K] bf16 ----------
template<int NZ>
__global__ __launch_bounds__(256) void wconv_kernel(
    const float* __restrict__ Wa, const float* __restrict__ Wb,
    const float* __restrict__ Wc, const float* __restrict__ Wd,
    u16* __restrict__ Da, u16* __restrict__ Db, u16* __restrict__ Dc, u16* __restrict__ Dd,
    int K, int N){
  __shared__ float tl[32][33];
  int z = (NZ>1) ? blockIdx.z : 0;
  const float* W = (z==0)?Wa:(z==1)?Wb:(z==2)?Wc:Wd;
  u16* Wt = (z==0)?Da:(z==1)?Db:(z==2)?Dc:Dd;
  int tx = threadIdx.x & 31, ty = threadIdx.x >> 5;
  int k0 = blockIdx.x * 32, n0 = blockIdx.y * 32;
  #pragma unroll
  for (int p=0;p<4;p++)
    tl[ty+8*p][tx] = W[(size_t)(k0+ty+8*p)*N + (n0+tx)];
  __syncthreads();
  #pragma unroll
  for (int p=0;p<4;p++){
    int n = ty+8*p;
    Wt[(size_t)(n0+n)*K + (k0+tx)] = f2bf(tl[tx][n]);
  }
}

// ---------- W1 (768x3072) + W2 (3072x768) transpose in one launch ----------
__global__ __launch_bounds__(256) void wconv2_kernel(
    const float* __restrict__ W1, const float* __restrict__ W2,
    u16* __restrict__ D1, u16* __restrict__ D2){
  __shared__ float tl[32][33];
  int z = blockIdx.z;
  const float* W = z ? W2 : W1;
  u16* Wt = z ? D2 : D1;
  int K = z ? 3072 : 768, N = z ? 768 : 3072;
  int k0 = (z ? blockIdx.y : blockIdx.x) * 32;
  int n0 = (z ? blockIdx.x : blockIdx.y) * 32;
  int tx = threadIdx.x & 31, ty = threadIdx.x >> 5;
  #pragma unroll
  for (int p=0;p<4;p++)
    tl[ty+8*p][tx] = W[(size_t)(k0+ty+8*p)*N + (n0+tx)];
  __syncthreads();
  #pragma unroll
  for (int p=0;p<4;p++){
    int n = ty+8*p;
    Wt[(size_t)(n0+n)*K + (k0+tx)] = f2bf(tl[tx][n]);
  }
}

// ---------- layernorm: in (f32 or bf16) [rows][768] -> bf16 out ----------
template<bool INBF16>
__global__ __launch_bounds__(256) void ln_kernel(const void* __restrict__ xin,
                                                 const float* __restrict__ g,
                                                 const float* __restrict__ bta,
                                                 u16* __restrict__ out){
  int row = blockIdx.x, t = threadIdx.x;
  float v0, v1, v2;
  if (INBF16){
    const u16* xr = (const u16*)xin + (size_t)row*768;
    v0 = bf2f(xr[t]); v1 = bf2f(xr[t+256]); v2 = bf2f(xr[t+512]);
  } else {
    const float* xr = (const float*)xin + (size_t)row*768;
    v0 = xr[t]; v1 = xr[t+256]; v2 = xr[t+512];
  }
  float s = v0+v1+v2, s2 = v0*v0+v1*v1+v2*v2;
  #pragma unroll
  for (int m=1;m<64;m<<=1){ s += __shfl_xor(s,m); s2 += __shfl_xor(s2,m); }
  __shared__ float ls[4], ls2[4];
  int w = t>>6;
  if ((t&63)==0){ ls[w]=s; ls2[w]=s2; }
  __syncthreads();
  s = ls[0]+ls[1]+ls[2]+ls[3]; s2 = ls2[0]+ls2[1]+ls2[2]+ls2[3];
  float mu = s*(1.0f/768.0f);
  float rstd = rsqrtf(s2*(1.0f/768.0f) - mu*mu + 1e-5f);
  u16* orow = out + (size_t)row*768;
  orow[t]     = f2bf((v0-mu)*rstd*g[t]     + bta[t]);
  orow[t+256] = f2bf((v1-mu)*rstd*g[t+256] + bta[t+256]);
  orow[t+512] = f2bf((v2-mu)*rstd*g[t+512] + bta[t+512]);
}

// ---------- GEMM: BK=64, granule-swizzled LDS, templated tile-M ----------
// VPERM: z==2 (V) output written directly to vtb in per-head transposed
// k-interleaved layout (pairs (k,k+16) adjacent). RESBF16: residual as bf16.
// NOTE (r16): XCD-aware A-major block remap REGRESSED ~4-5us -- keep plain.
template<bool GELU, bool RES, bool OUTBF16, int BM, bool VPERM=false, bool RESBF16=false>
__global__ __launch_bounds__(256) void gemm_kernel(
    const u16* __restrict__ A, const u16* __restrict__ Bt0, size_t btStride,
    const float* __restrict__ bias0, const float* __restrict__ bias1, const float* __restrict__ bias2,
    const void* __restrict__ res, void* __restrict__ out0, size_t outStride,
    int M, int N, int K, float qscale, u32* __restrict__ vtb = nullptr)
{
  constexpr int AM = BM/32;            // M-frags per wave (4 or 2)
  __shared__ u16 As[BM*64];
  __shared__ u16 Bs[128*64];
  const int t = threadIdx.x, lane = t & 63, w = t >> 6;
  const int lj = lane & 15, g = lane >> 4;
  const int wm = w >> 1, wn = w & 1;
  const int z = blockIdx.z;
  const u16* Bt = Bt0 + (size_t)z * btStride;
  const float* bias = (z==0) ? bias0 : (z==1 ? bias1 : bias2);
  const u16* Arow = A  + (size_t)blockIdx.x * BM * K;
  const u16* Brow = Bt + (size_t)blockIdx.y * 128 * K;

  f32x4 acc[AM][4];
  #pragma unroll
  for (int a=0;a<AM;a++)
    #pragma unroll
    for (int b=0;b<4;b++){ f32x4 zz = {0.f,0.f,0.f,0.f}; acc[a][b] = zz; }

  for (int kk=0; kk<K; kk+=64){
    #pragma unroll
    for (int cc=0;cc<BM/32;cc++){
      int c = cc*256 + t;
      int row = c>>3, gp = c&7;
      gload16(Arow + (size_t)row*K + kk + ((gp ^ (row&7))<<3),
              (void*)(As + (size_t)(cc*256 + w*64)*8));
    }
    #pragma unroll
    for (int cc=0;cc<4;cc++){
      int c = cc*256 + t;
      int row = c>>3, gp = c&7;
      gload16(Brow + (size_t)row*K + kk + ((gp ^ (row&7))<<3),
              (void*)(Bs + (size_t)(cc*256 + w*64)*8));
    }
    __syncthreads();                    // drains vmcnt: DMA writes visible
    #pragma unroll
    for (int ks=0;ks<2;ks++){
      s16x8 af[AM], bfr[4];
      #pragma unroll
      for (int mt=0;mt<AM;mt++){
        int row = wm*(BM/2)+mt*16+lj;
        af[mt]  = *(const s16x8*)&As[(size_t)row*64 + (((ks*4+g) ^ (lj&7))<<3)];
      }
      #pragma unroll
      for (int nt=0;nt<4;nt++){
        int row = wn*64+nt*16+lj;
        bfr[nt] = *(const s16x8*)&Bs[(size_t)row*64 + (((ks*4+g) ^ (lj&7))<<3)];
      }
      #pragma unroll
      for (int mt=0;mt<AM;mt++)
        #pragma unroll
        for (int nt=0;nt<4;nt++)
          acc[mt][nt] = __builtin_amdgcn_mfma_f32_16x16x32_bf16(af[mt], bfr[nt], acc[mt][nt], 0,0,0);
    }
    __syncthreads();                    // readers done before next stage
  }

  const size_t gr0 = (size_t)blockIdx.x*BM + wm*(BM/2);
  const int gc0 = blockIdx.y*128 + wn*64;

  if (VPERM && z == 2){
    // direct V write: vtb[bh][d][4096 k-perm], one dword per (mt-pair, nt, r)
    const int b_ = (int)(gr0 >> 12);
    const int kt = (int)((gr0 & 4095) >> 6);   // constant per (block,wm)
    #pragma unroll
    for (int mt2=0; mt2<AM; mt2+=2){
      const u32 gnq = 4*(mt2>>1) + g;          // granule index within 64-k tile
      #pragma unroll
      for (int nt=0;nt<4;nt++){
        int gc = gc0 + nt*16 + lj;
        int hh = gc>>6, dd = gc&63;
        float bv = bias[gc];
        size_t base = ((size_t)(b_*12+hh)*64 + dd)*2048 + (size_t)kt*32 + gnq*4;
        #pragma unroll
        for (int r=0;r<4;r++){
          float ve = acc[mt2][nt][r]   + bv;
          float vo = acc[mt2+1][nt][r] + bv;
          vtb[base + r] = cvtpk_bf16(ve, vo);
        }
      }
    }
    return;
  }

  float* outF = (float*)out0; u16* outB = (u16*)out0;
  if (OUTBF16) outB += (size_t)z*outStride; else outF += (size_t)z*outStride;
  #pragma unroll
  for (int mt=0;mt<AM;mt++)
    #pragma unroll
    for (int nt=0;nt<4;nt++){
      int gc = gc0 + nt*16 + lj;
      float bv = bias[gc];
      #pragma unroll
      for (int r=0;r<4;r++){
        size_t gr = gr0 + mt*16 + g*4 + r;
        float val = acc[mt][nt][r] + bv;
        if (z==0) val *= qscale;
        if (RES){
          if (RESBF16) val += bf2f(((const u16*)res)[gr*(size_t)N + gc]);
          else         val += ((const float*)res)[gr*(size_t)N + gc];
        }
        if (GELU) val = gelu_tanh(val);
        if (OUTBF16) outB[gr*(size_t)N + gc] = f2bf(val);
        else         outF[gr*(size_t)N + gc] = val;
      }
    }
}

// ---------- attention: XCD bh-cluster + T14 K-prefetch-to-registers ----------
// Block = (b,h,q-quarter,pair pp): iw=pp then 15-pp -> 17 units, 3 blocks/CU.
// XCD remap bx=(id%8)*96+id/8: FETCH 115MB->23.5MB measured (r16).
// One 32KB KV buffer. Per window: ds_write prefetched K (regs) -> bar -> QK ->
// bar -> issue V gload_lds + issue NEXT K global->reg loads (latency hides
// under softmax+PV) -> softmax -> bar (vmcnt drain) -> PV. Only the very first
// window uses gload_lds for K; phase boundary wraps prefetch to window 0.
// Swapped QK (S^T lane-local), in-register P via cvtpk, deferred normalization.
// launch_bounds(256,3): (256,4) forces 64-VGPR target and spills sacc (r5,r9).
__global__ __launch_bounds__(256,3) void attn_kernel(
    const u16* __restrict__ qb, const u16* __restrict__ kb,
    const u16* __restrict__ vtb, u16* __restrict__ ctx)
{
  __shared__ u16 KV[256*64];       // K: [krow 256][8 gran, ^=(krow&7)] ; V: [d 64][32 gran, ^=(d&15)]
  const int t = threadIdx.x, lane = t & 63, w = t >> 6;
  const int lj = lane & 15, g = lane >> 4;
  const int bx = (blockIdx.x & 7) * 96 + (blockIdx.x >> 3);   // XCD-cluster by bh
  const int pp = bx & 7, qq = (bx >> 3) & 3, bh = bx >> 5;
  const int h = bh % 12, b = bh / 12;
  const size_t seqbase = (size_t)b * 4096;
  const int hoff = h * 64;

  u32x4 kreg[8];                   // prefetched next-window K granules

  #pragma unroll
  for (int f=0; f<2; f++){
    const int iw = f ? (15 - pp) : pp;
    const int qrow0 = iw*256 + qq*64 + w*16;

    s16x8 qa[2];
    #pragma unroll
    for (int ks=0;ks<2;ks++)
      qa[ks] = *(const s16x8*)(qb + (seqbase + qrow0 + lj)*768 + hoff + ks*32 + g*8);

    f32x4 cacc[4];
    #pragma unroll
    for (int dt=0;dt<4;dt++){ f32x4 zz = {0.f,0.f,0.f,0.f}; cacc[dt] = zz; }

    for (int jw=0; jw<=iw; jw++){
      const u16* kwin = kb + (seqbase + jw*256)*768 + hoff;
      const u16* vtwin = vtb + (size_t)bh*64*4096 + jw*256;

      __syncthreads();                       // prev PV reads done before K overwrite
      if (f == 0 && jw == 0){
        #pragma unroll
        for (int cc=0;cc<8;cc++){
          int c = cc*256 + t;
          int krow = c>>3, vp = c&7;
          gload16(kwin + (size_t)krow*768 + ((vp ^ (krow&7))<<3),
                  (void*)(KV + (size_t)(cc*256 + w*64)*8));
        }
      } else {
        // K already in registers (prefetched last window): plain LDS writes
        #pragma unroll
        for (int cc=0;cc<8;cc++){
          int c = cc*256 + t;
          *(u32x4*)&KV[(size_t)c*8] = kreg[cc];
        }
      }
      __syncthreads();                       // K visible

      // swapped QK: sacc[kt][r] = S^T[k = kt*16+4g+r][q = lj]
      f32x4 sacc[16];
      #pragma unroll
      for (int kt=0;kt<16;kt++){ f32x4 zz = {0.f,0.f,0.f,0.f}; sacc[kt] = zz; }
      __builtin_amdgcn_s_setprio(1);
      #pragma unroll
      for (int kt=0;kt<16;kt++){
        int kl = kt*16 + lj;
        #pragma unroll
        for (int ks=0;ks<2;ks++){
          s16x8 kf = *(const s16x8*)&KV[ (size_t)kl*64 + (((4*ks+g) ^ (kl&7))<<3) ];
          sacc[kt] = __builtin_amdgcn_mfma_f32_16x16x32_bf16(kf, qa[ks], sacc[kt], 0,0,0);
        }
      }
      __builtin_amdgcn_s_setprio(0);
      __syncthreads();                       // QK reads of KV done

      // stage V (perm layout) -- latency hides under softmax below
      #pragma unroll
      for (int cc=0;cc<8;cc++){
        int c = cc*256 + t;
        int d = c>>5, cp = c&31;
        gload16(vtwin + (size_t)d*4096 + ((cp ^ (d&15))<<3),
                (void*)(KV + (size_t)(cc*256 + w*64)*8));
      }
      // prefetch NEXT window's K into registers (wraps to window 0 at phase end)
      {
        int jn = (jw < iw) ? (jw + 1) : 0;
        const u16* kwn = kb + (seqbase + jn*256)*768 + hoff;
        #pragma unroll
        for (int cc=0;cc<8;cc++){
          int c = cc*256 + t;
          int krow = c>>3, vp = c&7;
          kreg[cc] = *(const u32x4*)(kwn + (size_t)krow*768 + ((vp ^ (krow&7))<<3));
        }
      }

      // softmax over 256 k for q=lj: in-lane exp2 + 2 cross-group shuffles
      float sm = 0.f;
      #pragma unroll
      for (int kt=0;kt<16;kt++)
        #pragma unroll
        for (int r=0;r<4;r++){
          float pv = fexp2(sacc[kt][r]);
          sacc[kt][r] = pv; sm += pv;
        }
      sm += __shfl_xor(sm, 16);
      sm += __shfl_xor(sm, 32);
      float rs = frcp(sm);

      __syncthreads();                       // V staged visible (drains vmcnt)

      // PV on RAW exp values into pacc; normalize once per window at the end
      f32x4 pacc[4];
      #pragma unroll
      for (int dt=0;dt<4;dt++){ f32x4 zz = {0.f,0.f,0.f,0.f}; pacc[dt] = zz; }
      #pragma unroll
      for (int ks=0;ks<8;ks++){
        u32x4 pw;
        #pragma unroll
        for (int r=0;r<4;r++)
          pw[r] = cvtpk_bf16(sacc[2*ks][r], sacc[2*ks+1][r]);
        s16x8 pa = __builtin_bit_cast(s16x8, pw);
        __builtin_amdgcn_s_setprio(1);
        #pragma unroll
        for (int dt=0;dt<4;dt++){
          int d = dt*16 + lj;
          s16x8 vf = *(const s16x8*)&KV[ (size_t)d*256 + (((4*ks+g) ^ (d&15))<<3) ];
          pacc[dt] = __builtin_amdgcn_mfma_f32_16x16x32_bf16(pa, vf, pacc[dt], 0,0,0);
        }
        __builtin_amdgcn_s_setprio(0);
      }
      #pragma unroll
      for (int dt=0;dt<4;dt++)
        #pragma unroll
        for (int r=0;r<4;r++)
          cacc[dt][r] += rs * pacc[dt][r];
    }

    #pragma unroll
    for (int dt=0;dt<4;dt++)
      #pragma unroll
      for (int r=0;r<4;r++){
        int qrow = qrow0 + g*4 + r;
        ctx[ (seqbase + qrow)*768 + hoff + dt*16 + lj ] = f2bf(cacc[dt][r]);
      }
  }
}

extern "C" void kernel_launch(void* const* d_in, const int* in_sizes, int n_in,
                              void* d_out, int out_size, void* d_ws, size_t ws_size,
                              hipStream_t stream)
{
  const float* x    = (const float*)d_in[0];
  const float* Wq   = (const float*)d_in[1];
  const float* bq   = (const float*)d_in[2];
  const float* Wk   = (const float*)d_in[3];
  const float* bk   = (const float*)d_in[4];
  const float* Wv   = (const float*)d_in[5];
  const float* bv   = (const float*)d_in[6];
  const float* Wo   = (const float*)d_in[7];
  const float* bo   = (const float*)d_in[8];
  const float* ln1g = (const float*)d_in[9];
  const float* ln1b = (const float*)d_in[10];
  const float* W1   = (const float*)d_in[11];
  const float* b1   = (const float*)d_in[12];
  const float* W2   = (const float*)d_in[13];
  const float* b2   = (const float*)d_in[14];
  const float* ln2g = (const float*)d_in[15];
  const float* ln2b = (const float*)d_in[16];

  char* ws = (char*)d_ws;
  constexpr size_t SZ_W768  = (size_t)768*768*2;
  constexpr size_t SZ_W3072 = (size_t)768*3072*2;
  constexpr size_t SZ_HB    = (size_t)8192*768*2;
  u16* wtq = (u16*)(ws);
  u16* wtk = (u16*)(ws + SZ_W768);
  u16* wtv = (u16*)(ws + 2*SZ_W768);
  u16* wto = (u16*)(ws + 3*SZ_W768);
  u16* wt1 = (u16*)(ws + 4*SZ_W768);
  u16* wt2 = (u16*)(ws + 4*SZ_W768 + SZ_W3072);
  char* p0 = ws + 4*SZ_W768 + 2*SZ_W3072;
  u16*   hbuf  = (u16*)p0;              // LN1/LN2 out (bf16)
  u16*   qbuf  = (u16*)(p0 + SZ_HB);
  u16*   kbuf  = (u16*)(p0 + 2*SZ_HB);
  u16*   vtbuf = (u16*)(p0 + 3*SZ_HB);  // V written DIRECTLY in perm layout by QKV
  u16*   cbuf  = (u16*)(p0 + 4*SZ_HB);
  u16*   x1    = (u16*)(p0 + 5*SZ_HB);  // attention residual stream, bf16
  u16*   ffa   = qbuf;                  // FF activations span slots 1-4
  float* outp  = (float*)d_out;

  // weight transpose + f32->bf16: 4 square weights in one launch; W1+W2 in one
  wconv_kernel<4><<<dim3(24,24,4), 256, 0, stream>>>(
      Wq, Wk, Wv, Wo, wtq, wtk, wtv, wto, 768, 768);
  wconv2_kernel<<<dim3(24,96,2), 256, 0, stream>>>(W1, W2, wt1, wt2);

  // LN1 -> hbuf
  ln_kernel<false><<<8192, 256, 0, stream>>>(x, ln1g, ln1b, hbuf);
  // QKV (z-fused, BM=128); Q pre-scaled by (1/8)*log2(e); V -> vtbuf direct
  gemm_kernel<false,false,true,128,true><<<dim3(64,6,3), 256, 0, stream>>>(
      hbuf, wtq, (size_t)768*768, bq, bk, bv, nullptr, qbuf, (size_t)8192*768,
      8192, 768, 768, 0.180336880111f, (u32*)vtbuf);
  // attention
  attn_kernel<<<768, 256, 0, stream>>>(qbuf, kbuf, vtbuf, cbuf);
  // Wo + residual(x, f32) -> x1 (bf16); BM=64 -> 768 blocks, 3/CU balanced
  gemm_kernel<false,true,true,64><<<dim3(128,6,1), 256, 0, stream>>>(
      cbuf, wto, 0, bo, bo, bo, x, x1, 0, 8192, 768, 768, 1.0f);
  // LN2 (bf16 in) -> hbuf (bf16)
  ln_kernel<true><<<8192, 256, 0, stream>>>(x1, ln2g, ln2b, hbuf);
  // FF1 + tanh-gelu -> ffa (bf16)
  gemm_kernel<true,false,true,128><<<dim3(64,24,1), 256, 0, stream>>>(
      hbuf, wt1, 0, b1, b1, b1, nullptr, ffa, 0, 8192, 3072, 768, 1.0f);
  // FF2 + residual(x1, bf16) -> out (f32); BM=64 -> 768 blocks, 3/CU
  gemm_kernel<false,true,false,64,false,true><<<dim3(128,6,1), 256, 0, stream>>>(
      ffa, wt2, 0, b2, b2, b2, x1, outp, 0, 8192, 768, 3072, 1.0f);
}

// Round 19
// 271.523 us; speedup vs baseline: 1.2448x; 1.2448x over previous
//
#include <hip/hip_runtime.h>
#include <cstdint>
#include <cstddef>

#define DEV __device__ __forceinline__

typedef unsigned short u16;
typedef unsigned int u32;
typedef __attribute__((ext_vector_type(8))) short s16x8;   // 8 x bf16 (raw bits)
typedef __attribute__((ext_vector_type(4))) float f32x4;
typedef __attribute__((ext_vector_type(4))) unsigned int u32x4;
typedef __attribute__((ext_vector_type(2))) unsigned int u32x2;

typedef unsigned int u32_as1 __attribute__((address_space(1)));
typedef unsigned int u32_as3 __attribute__((address_space(3)));

DEV u16 f2bf(float f){
  unsigned u = __float_as_uint(f);
  u += 0x7fffu + ((u >> 16) & 1u);   // RNE
  return (u16)(u >> 16);
}

DEV float bf2f(u16 v){ return __uint_as_float(((u32)v) << 16); }

DEV u32 cvtpk_bf16(float lo, float hi){
  u32 r;
  asm("v_cvt_pk_bf16_f32 %0, %1, %2" : "=v"(r) : "v"(lo), "v"(hi));
  return r;
}

DEV float fexp2(float x){            // 2^x, single v_exp_f32
  float r;
  asm("v_exp_f32 %0, %1" : "=v"(r) : "v"(x));
  return r;
}

DEV float frcp(float x){             // 1/x, single v_rcp_f32 (1 ulp)
  float r;
  asm("v_rcp_f32 %0, %1" : "=v"(r) : "v"(x));
  return r;
}

DEV void gload16(const void* g, void* l){
  // async global->LDS, 16B per lane; LDS dest = wave-uniform base + lane*16
  __builtin_amdgcn_global_load_lds((const u32_as1*)g, (u32_as3*)l, 16, 0, 0);
}

// tanh-GELU via one exp2: x * t/(t+1), t = exp2(2.3022083*(x + 0.044715 x^3)).
// |err vs erf-GELU| < 4e-4. z clamped to 100 so t never overflows to inf.
DEV float gelu_tanh(float x){
  float x2 = x*x;
  float z = 2.3022083f * x * fmaf(x2, 0.044715f, 1.0f);
  z = fminf(z, 100.0f);
  float t = fexp2(z);
  return x * t * frcp(t + 1.0f);
}

// ---------- weight transpose+convert: W[K][N] f32 -> Wt[N][K] bf16 ----------
template<int NZ>
__global__ __launch_bounds__(256) void wconv_kernel(
    const float* __restrict__ Wa, const float* __restrict__ Wb,
    const float* __restrict__ Wc, const float* __restrict__ Wd,
    u16* __restrict__ Da, u16* __restrict__ Db, u16* __restrict__ Dc, u16* __restrict__ Dd,
    int K, int N){
  __shared__ float tl[32][33];
  int z = (NZ>1) ? blockIdx.z : 0;
  const float* W = (z==0)?Wa:(z==1)?Wb:(z==2)?Wc:Wd;
  u16* Wt = (z==0)?Da:(z==1)?Db:(z==2)?Dc:Dd;
  int tx = threadIdx.x & 31, ty = threadIdx.x >> 5;
  int k0 = blockIdx.x * 32, n0 = blockIdx.y * 32;
  #pragma unroll
  for (int p=0;p<4;p++)
    tl[ty+8*p][tx] = W[(size_t)(k0+ty+8*p)*N + (n0+tx)];
  __syncthreads();
  #pragma unroll
  for (int p=0;p<4;p++){
    int n = ty+8*p;
    Wt[(size_t)(n0+n)*K + (k0+tx)] = f2bf(tl[tx][n]);
  }
}

// ---------- W1 (768x3072) + W2 (3072x768) transpose in one launch ----------
__global__ __launch_bounds__(256) void wconv2_kernel(
    const float* __restrict__ W1, const float* __restrict__ W2,
    u16* __restrict__ D1, u16* __restrict__ D2){
  __shared__ float tl[32][33];
  int z = blockIdx.z;
  const float* W = z ? W2 : W1;
  u16* Wt = z ? D2 : D1;
  int K = z ? 3072 : 768, N = z ? 768 : 3072;
  int k0 = (z ? blockIdx.y : blockIdx.x) * 32;
  int n0 = (z ? blockIdx.x : blockIdx.y) * 32;
  int tx = threadIdx.x & 31, ty = threadIdx.x >> 5;
  #pragma unroll
  for (int p=0;p<4;p++)
    tl[ty+8*p][tx] = W[(size_t)(k0+ty+8*p)*N + (n0+tx)];
  __syncthreads();
  #pragma unroll
  for (int p=0;p<4;p++){
    int n = ty+8*p;
    Wt[(size_t)(n0+n)*K + (k0+tx)] = f2bf(tl[tx][n]);
  }
}

// ---------- layernorm: in (f32 or bf16) [rows][768] -> bf16 out ----------
template<bool INBF16>
__global__ __launch_bounds__(256) void ln_kernel(const void* __restrict__ xin,
                                                 const float* __restrict__ g,
                                                 const float* __restrict__ bta,
                                                 u16* __restrict__ out){
  int row = blockIdx.x, t = threadIdx.x;
  float v0, v1, v2;
  if (INBF16){
    const u16* xr = (const u16*)xin + (size_t)row*768;
    v0 = bf2f(xr[t]); v1 = bf2f(xr[t+256]); v2 = bf2f(xr[t+512]);
  } else {
    const float* xr = (const float*)xin + (size_t)row*768;
    v0 = xr[t]; v1 = xr[t+256]; v2 = xr[t+512];
  }
  float s = v0+v1+v2, s2 = v0*v0+v1*v1+v2*v2;
  #pragma unroll
  for (int m=1;m<64;m<<=1){ s += __shfl_xor(s,m); s2 += __shfl_xor(s2,m); }
  __shared__ float ls[4], ls2[4];
  int w = t>>6;
  if ((t&63)==0){ ls[w]=s; ls2[w]=s2; }
  __syncthreads();
  s = ls[0]+ls[1]+ls[2]+ls[3]; s2 = ls2[0]+ls2[1]+ls2[2]+ls2[3];
  float mu = s*(1.0f/768.0f);
  float rstd = rsqrtf(s2*(1.0f/768.0f) - mu*mu + 1e-5f);
  u16* orow = out + (size_t)row*768;
  orow[t]     = f2bf((v0-mu)*rstd*g[t]     + bta[t]);
  orow[t+256] = f2bf((v1-mu)*rstd*g[t+256] + bta[t+256]);
  orow[t+512] = f2bf((v2-mu)*rstd*g[t+512] + bta[t+512]);
}

// ---------- GEMM: BK=64, granule-swizzled LDS, templated tile-M ----------
// VPERM: z==2 (V) output written directly to vtb in per-head transposed
// k-interleaved layout (pairs (k,k+16) adjacent). RESBF16: residual as bf16.
// NOTE (r16): XCD-aware A-major block remap REGRESSED ~4-5us -- keep plain.
template<bool GELU, bool RES, bool OUTBF16, int BM, bool VPERM=false, bool RESBF16=false>
__global__ __launch_bounds__(256) void gemm_kernel(
    const u16* __restrict__ A, const u16* __restrict__ Bt0, size_t btStride,
    const float* __restrict__ bias0, const float* __restrict__ bias1, const float* __restrict__ bias2,
    const void* __restrict__ res, void* __restrict__ out0, size_t outStride,
    int M, int N, int K, float qscale, u32* __restrict__ vtb = nullptr)
{
  constexpr int AM = BM/32;            // M-frags per wave (4 or 2)
  __shared__ u16 As[BM*64];
  __shared__ u16 Bs[128*64];
  const int t = threadIdx.x, lane = t & 63, w = t >> 6;
  const int lj = lane & 15, g = lane >> 4;
  const int wm = w >> 1, wn = w & 1;
  const int z = blockIdx.z;
  const u16* Bt = Bt0 + (size_t)z * btStride;
  const float* bias = (z==0) ? bias0 : (z==1 ? bias1 : bias2);
  const u16* Arow = A  + (size_t)blockIdx.x * BM * K;
  const u16* Brow = Bt + (size_t)blockIdx.y * 128 * K;

  f32x4 acc[AM][4];
  #pragma unroll
  for (int a=0;a<AM;a++)
    #pragma unroll
    for (int b=0;b<4;b++){ f32x4 zz = {0.f,0.f,0.f,0.f}; acc[a][b] = zz; }

  for (int kk=0; kk<K; kk+=64){
    #pragma unroll
    for (int cc=0;cc<BM/32;cc++){
      int c = cc*256 + t;
      int row = c>>3, gp = c&7;
      gload16(Arow + (size_t)row*K + kk + ((gp ^ (row&7))<<3),
              (void*)(As + (size_t)(cc*256 + w*64)*8));
    }
    #pragma unroll
    for (int cc=0;cc<4;cc++){
      int c = cc*256 + t;
      int row = c>>3, gp = c&7;
      gload16(Brow + (size_t)row*K + kk + ((gp ^ (row&7))<<3),
              (void*)(Bs + (size_t)(cc*256 + w*64)*8));
    }
    __syncthreads();                    // drains vmcnt: DMA writes visible
    #pragma unroll
    for (int ks=0;ks<2;ks++){
      s16x8 af[AM], bfr[4];
      #pragma unroll
      for (int mt=0;mt<AM;mt++){
        int row = wm*(BM/2)+mt*16+lj;
        af[mt]  = *(const s16x8*)&As[(size_t)row*64 + (((ks*4+g) ^ (lj&7))<<3)];
      }
      #pragma unroll
      for (int nt=0;nt<4;nt++){
        int row = wn*64+nt*16+lj;
        bfr[nt] = *(const s16x8*)&Bs[(size_t)row*64 + (((ks*4+g) ^ (lj&7))<<3)];
      }
      #pragma unroll
      for (int mt=0;mt<AM;mt++)
        #pragma unroll
        for (int nt=0;nt<4;nt++)
          acc[mt][nt] = __builtin_amdgcn_mfma_f32_16x16x32_bf16(af[mt], bfr[nt], acc[mt][nt], 0,0,0);
    }
    __syncthreads();                    // readers done before next stage
  }

  const size_t gr0 = (size_t)blockIdx.x*BM + wm*(BM/2);
  const int gc0 = blockIdx.y*128 + wn*64;

  if (VPERM && z == 2){
    // direct V write: vtb[bh][d][4096 k-perm], one dword per (mt-pair, nt, r)
    const int b_ = (int)(gr0 >> 12);
    const int kt = (int)((gr0 & 4095) >> 6);   // constant per (block,wm)
    #pragma unroll
    for (int mt2=0; mt2<AM; mt2+=2){
      const u32 gnq = 4*(mt2>>1) + g;          // granule index within 64-k tile
      #pragma unroll
      for (int nt=0;nt<4;nt++){
        int gc = gc0 + nt*16 + lj;
        int hh = gc>>6, dd = gc&63;
        float bv = bias[gc];
        size_t base = ((size_t)(b_*12+hh)*64 + dd)*2048 + (size_t)kt*32 + gnq*4;
        #pragma unroll
        for (int r=0;r<4;r++){
          float ve = acc[mt2][nt][r]   + bv;
          float vo = acc[mt2+1][nt][r] + bv;
          vtb[base + r] = cvtpk_bf16(ve, vo);
        }
      }
    }
    return;
  }

  float* outF = (float*)out0; u16* outB = (u16*)out0;
  if (OUTBF16) outB += (size_t)z*outStride; else outF += (size_t)z*outStride;
  #pragma unroll
  for (int mt=0;mt<AM;mt++)
    #pragma unroll
    for (int nt=0;nt<4;nt++){
      int gc = gc0 + nt*16 + lj;
      float bv = bias[gc];
      #pragma unroll
      for (int r=0;r<4;r++){
        size_t gr = gr0 + mt*16 + g*4 + r;
        float val = acc[mt][nt][r] + bv;
        if (z==0) val *= qscale;
        if (RES){
          if (RESBF16) val += bf2f(((const u16*)res)[gr*(size_t)N + gc]);
          else         val += ((const float*)res)[gr*(size_t)N + gc];
        }
        if (GELU) val = gelu_tanh(val);
        if (OUTBF16) outB[gr*(size_t)N + gc] = f2bf(val);
        else         outF[gr*(size_t)N + gc] = val;
      }
    }
}

// ---------- attention (proven structure + XCD-aware bh-cluster remap) ----------
// Block = (b,h,q-quarter,pair pp): iw=pp then 15-pp -> 17 units, 3 blocks/CU.
// XCD remap bx=(id%8)*96+id/8: each XCD owns 3 whole (b,h) slices; their K+V
// (3MB) fit the 4MB per-XCD L2 -> FETCH_SIZE 115MB->23.5MB measured (r16).
// One 32KB KV buffer: K -> QK -> stage V under softmax -> PV raw -> cacc+=rs*pacc.
// Swapped QK (S^T lane-local), in-register P via cvtpk, deferred normalization.
// launch_bounds(256,3): (256,4) forces 64-VGPR target and spills sacc (r5,r9).
// r18: K-prefetch-to-registers (+32 VGPR) spilled to scratch (WRITE 142MB) --
// this kernel has no VGPR headroom at 84; do not add register state.
__global__ __launch_bounds__(256,3) void attn_kernel(
    const u16* __restrict__ qb, const u16* __restrict__ kb,
    const u16* __restrict__ vtb, u16* __restrict__ ctx)
{
  __shared__ u16 KV[256*64];       // K: [krow 256][8 gran, ^=(krow&7)] ; V: [d 64][32 gran, ^=(d&15)]
  const int t = threadIdx.x, lane = t & 63, w = t >> 6;
  const int lj = lane & 15, g = lane >> 4;
  const int bx = (blockIdx.x & 7) * 96 + (blockIdx.x >> 3);   // XCD-cluster by bh
  const int pp = bx & 7, qq = (bx >> 3) & 3, bh = bx >> 5;
  const int h = bh % 12, b = bh / 12;
  const size_t seqbase = (size_t)b * 4096;
  const int hoff = h * 64;

  #pragma unroll
  for (int f=0; f<2; f++){
    const int iw = f ? (15 - pp) : pp;
    const int qrow0 = iw*256 + qq*64 + w*16;

    s16x8 qa[2];
    #pragma unroll
    for (int ks=0;ks<2;ks++)
      qa[ks] = *(const s16x8*)(qb + (seqbase + qrow0 + lj)*768 + hoff + ks*32 + g*8);

    f32x4 cacc[4];
    #pragma unroll
    for (int dt=0;dt<4;dt++){ f32x4 zz = {0.f,0.f,0.f,0.f}; cacc[dt] = zz; }

    for (int jw=0; jw<=iw; jw++){
      const u16* kwin = kb + (seqbase + jw*256)*768 + hoff;
      const u16* vtwin = vtb + (size_t)bh*64*4096 + jw*256;

      __syncthreads();                       // prev PV reads done before K overwrite
      #pragma unroll
      for (int cc=0;cc<8;cc++){
        int c = cc*256 + t;
        int krow = c>>3, vp = c&7;
        gload16(kwin + (size_t)krow*768 + ((vp ^ (krow&7))<<3),
                (void*)(KV + (size_t)(cc*256 + w*64)*8));
      }
      __syncthreads();                       // K visible

      // swapped QK: sacc[kt][r] = S^T[k = kt*16+4g+r][q = lj]
      f32x4 sacc[16];
      #pragma unroll
      for (int kt=0;kt<16;kt++){ f32x4 zz = {0.f,0.f,0.f,0.f}; sacc[kt] = zz; }
      __builtin_amdgcn_s_setprio(1);
      #pragma unroll
      for (int kt=0;kt<16;kt++){
        int kl = kt*16 + lj;
        #pragma unroll
        for (int ks=0;ks<2;ks++){
          s16x8 kf = *(const s16x8*)&KV[ (size_t)kl*64 + (((4*ks+g) ^ (kl&7))<<3) ];
          sacc[kt] = __builtin_amdgcn_mfma_f32_16x16x32_bf16(kf, qa[ks], sacc[kt], 0,0,0);
        }
      }
      __builtin_amdgcn_s_setprio(0);
      __syncthreads();                       // QK reads of KV done

      // stage V (perm layout) -- latency hides under softmax below
      #pragma unroll
      for (int cc=0;cc<8;cc++){
        int c = cc*256 + t;
        int d = c>>5, cp = c&31;
        gload16(vtwin + (size_t)d*4096 + ((cp ^ (d&15))<<3),
                (void*)(KV + (size_t)(cc*256 + w*64)*8));
      }

      // softmax over 256 k for q=lj: in-lane exp2 + 2 cross-group shuffles
      float sm = 0.f;
      #pragma unroll
      for (int kt=0;kt<16;kt++)
        #pragma unroll
        for (int r=0;r<4;r++){
          float pv = fexp2(sacc[kt][r]);
          sacc[kt][r] = pv; sm += pv;
        }
      sm += __shfl_xor(sm, 16);
      sm += __shfl_xor(sm, 32);
      float rs = frcp(sm);

      __syncthreads();                       // V staged visible (drains vmcnt)

      // PV on RAW exp values into pacc; normalize once per window at the end
      f32x4 pacc[4];
      #pragma unroll
      for (int dt=0;dt<4;dt++){ f32x4 zz = {0.f,0.f,0.f,0.f}; pacc[dt] = zz; }
      #pragma unroll
      for (int ks=0;ks<8;ks++){
        u32x4 pw;
        #pragma unroll
        for (int r=0;r<4;r++)
          pw[r] = cvtpk_bf16(sacc[2*ks][r], sacc[2*ks+1][r]);
        s16x8 pa = __builtin_bit_cast(s16x8, pw);
        __builtin_amdgcn_s_setprio(1);
        #pragma unroll
        for (int dt=0;dt<4;dt++){
          int d = dt*16 + lj;
          s16x8 vf = *(const s16x8*)&KV[ (size_t)d*256 + (((4*ks+g) ^ (d&15))<<3) ];
          pacc[dt] = __builtin_amdgcn_mfma_f32_16x16x32_bf16(pa, vf, pacc[dt], 0,0,0);
        }
        __builtin_amdgcn_s_setprio(0);
      }
      #pragma unroll
      for (int dt=0;dt<4;dt++)
        #pragma unroll
        for (int r=0;r<4;r++)
          cacc[dt][r] += rs * pacc[dt][r];
    }

    #pragma unroll
    for (int dt=0;dt<4;dt++)
      #pragma unroll
      for (int r=0;r<4;r++){
        int qrow = qrow0 + g*4 + r;
        ctx[ (seqbase + qrow)*768 + hoff + dt*16 + lj ] = f2bf(cacc[dt][r]);
      }
  }
}

extern "C" void kernel_launch(void* const* d_in, const int* in_sizes, int n_in,
                              void* d_out, int out_size, void* d_ws, size_t ws_size,
                              hipStream_t stream)
{
  const float* x    = (const float*)d_in[0];
  const float* Wq   = (const float*)d_in[1];
  const float* bq   = (const float*)d_in[2];
  const float* Wk   = (const float*)d_in[3];
  const float* bk   = (const float*)d_in[4];
  const float* Wv   = (const float*)d_in[5];
  const float* bv   = (const float*)d_in[6];
  const float* Wo   = (const float*)d_in[7];
  const float* bo   = (const float*)d_in[8];
  const float* ln1g = (const float*)d_in[9];
  const float* ln1b = (const float*)d_in[10];
  const float* W1   = (const float*)d_in[11];
  const float* b1   = (const float*)d_in[12];
  const float* W2   = (const float*)d_in[13];
  const float* b2   = (const float*)d_in[14];
  const float* ln2g = (const float*)d_in[15];
  const float* ln2b = (const float*)d_in[16];

  char* ws = (char*)d_ws;
  constexpr size_t SZ_W768  = (size_t)768*768*2;
  constexpr size_t SZ_W3072 = (size_t)768*3072*2;
  constexpr size_t SZ_HB    = (size_t)8192*768*2;
  u16* wtq = (u16*)(ws);
  u16* wtk = (u16*)(ws + SZ_W768);
  u16* wtv = (u16*)(ws + 2*SZ_W768);
  u16* wto = (u16*)(ws + 3*SZ_W768);
  u16* wt1 = (u16*)(ws + 4*SZ_W768);
  u16* wt2 = (u16*)(ws + 4*SZ_W768 + SZ_W3072);
  char* p0 = ws + 4*SZ_W768 + 2*SZ_W3072;
  u16*   hbuf  = (u16*)p0;              // LN1/LN2 out (bf16)
  u16*   qbuf  = (u16*)(p0 + SZ_HB);
  u16*   kbuf  = (u16*)(p0 + 2*SZ_HB);
  u16*   vtbuf = (u16*)(p0 + 3*SZ_HB);  // V written DIRECTLY in perm layout by QKV
  u16*   cbuf  = (u16*)(p0 + 4*SZ_HB);
  u16*   x1    = (u16*)(p0 + 5*SZ_HB);  // attention residual stream, bf16
  u16*   ffa   = qbuf;                  // FF activations span slots 1-4
  float* outp  = (float*)d_out;

  // weight transpose + f32->bf16: 4 square weights in one launch; W1+W2 in one
  wconv_kernel<4><<<dim3(24,24,4), 256, 0, stream>>>(
      Wq, Wk, Wv, Wo, wtq, wtk, wtv, wto, 768, 768);
  wconv2_kernel<<<dim3(24,96,2), 256, 0, stream>>>(W1, W2, wt1, wt2);

  // LN1 -> hbuf
  ln_kernel<false><<<8192, 256, 0, stream>>>(x, ln1g, ln1b, hbuf);
  // QKV (z-fused, BM=128); Q pre-scaled by (1/8)*log2(e); V -> vtbuf direct
  gemm_kernel<false,false,true,128,true><<<dim3(64,6,3), 256, 0, stream>>>(
      hbuf, wtq, (size_t)768*768, bq, bk, bv, nullptr, qbuf, (size_t)8192*768,
      8192, 768, 768, 0.180336880111f, (u32*)vtbuf);
  // attention
  attn_kernel<<<768, 256, 0, stream>>>(qbuf, kbuf, vtbuf, cbuf);
  // Wo + residual(x, f32) -> x1 (bf16); BM=64 -> 768 blocks, 3/CU balanced
  gemm_kernel<false,true,true,64><<<dim3(128,6,1), 256, 0, stream>>>(
      cbuf, wto, 0, bo, bo, bo, x, x1, 0, 8192, 768, 768, 1.0f);
  // LN2 (bf16 in) -> hbuf (bf16)
  ln_kernel<true><<<8192, 256, 0, stream>>>(x1, ln2g, ln2b, hbuf);
  // FF1 + tanh-gelu -> ffa (bf16)
  gemm_kernel<true,false,true,128><<<dim3(64,24,1), 256, 0, stream>>>(
      hbuf, wt1, 0, b1, b1, b1, nullptr, ffa, 0, 8192, 3072, 768, 1.0f);
  // FF2 + residual(x1, bf16) -> out (f32); BM=64 -> 768 blocks, 3/CU
  gemm_kernel<false,true,false,64,false,true><<<dim3(128,6,1), 256, 0, stream>>>(
      ffa, wt2, 0, b2, b2, b2, x1, outp, 0, 8192, 768, 3072, 1.0f);
}

// Round 20
// 266.225 us; speedup vs baseline: 1.2696x; 1.0199x over previous
//
#include <hip/hip_runtime.h>
#include <cstdint>
#include <cstddef>

#define DEV __device__ __forceinline__

typedef unsigned short u16;
typedef unsigned int u32;
typedef __attribute__((ext_vector_type(8))) short s16x8;   // 8 x bf16 (raw bits)
typedef __attribute__((ext_vector_type(4))) float f32x4;
typedef __attribute__((ext_vector_type(4))) unsigned int u32x4;

typedef unsigned int u32_as1 __attribute__((address_space(1)));
typedef unsigned int u32_as3 __attribute__((address_space(3)));

DEV u16 f2bf(float f){
  unsigned u = __float_as_uint(f);
  u += 0x7fffu + ((u >> 16) & 1u);   // RNE
  return (u16)(u >> 16);
}

DEV float bf2f(u16 v){ return __uint_as_float(((u32)v) << 16); }

DEV u32 cvtpk_bf16(float lo, float hi){
  u32 r;
  asm("v_cvt_pk_bf16_f32 %0, %1, %2" : "=v"(r) : "v"(lo), "v"(hi));
  return r;
}

DEV float fexp2(float x){            // 2^x, single v_exp_f32
  float r;
  asm("v_exp_f32 %0, %1" : "=v"(r) : "v"(x));
  return r;
}

DEV float frcp(float x){             // 1/x, single v_rcp_f32 (1 ulp)
  float r;
  asm("v_rcp_f32 %0, %1" : "=v"(r) : "v"(x));
  return r;
}

DEV void gload16(const void* g, void* l){
  // async global->LDS, 16B per lane; LDS dest = wave-uniform base + lane*16
  __builtin_amdgcn_global_load_lds((const u32_as1*)g, (u32_as3*)l, 16, 0, 0);
}

// tanh-GELU via one exp2: x * t/(t+1), t = exp2(2.3022083*(x + 0.044715 x^3)).
// |err vs erf-GELU| < 4e-4. z clamped to 100 so t never overflows to inf.
DEV float gelu_tanh(float x){
  float x2 = x*x;
  float z = 2.3022083f * x * fmaf(x2, 0.044715f, 1.0f);
  z = fminf(z, 100.0f);
  float t = fexp2(z);
  return x * t * frcp(t + 1.0f);
}

// ---------- prep: all 6 weight transposes + LN1, one launch ----------
// blocks [0,2304): square weights Wq/Wk/Wv/Wo (z=id/576, 24x24 tiles of 32x32)
// blocks [2304,4608): W1 768x3072 ; [4608,6912): W2 3072x768
// blocks [6912,15104): LN1 row = id-6912
__global__ __launch_bounds__(256) void prep_kernel(
    const float* __restrict__ Wq, const float* __restrict__ Wk,
    const float* __restrict__ Wv, const float* __restrict__ Wo,
    const float* __restrict__ W1, const float* __restrict__ W2,
    u16* __restrict__ wtq, u16* __restrict__ wtk, u16* __restrict__ wtv,
    u16* __restrict__ wto, u16* __restrict__ wt1, u16* __restrict__ wt2,
    const float* __restrict__ x, const float* __restrict__ g,
    const float* __restrict__ bta, u16* __restrict__ out)
{
  __shared__ float tl[32][33];
  __shared__ float ls[4], ls2[4];
  const int id = blockIdx.x, t = threadIdx.x;

  if (id < 6912){
    const float* W; u16* Wt; int K, N, k0, n0;
    if (id < 2304){
      int z = id / 576, r = id - z*576;
      W  = (z==0)?Wq:(z==1)?Wk:(z==2)?Wv:Wo;
      Wt = (z==0)?wtq:(z==1)?wtk:(z==2)?wtv:wto;
      K = 768; N = 768; k0 = (r/24)*32; n0 = (r%24)*32;
    } else if (id < 4608){
      int r = id - 2304;
      W = W1; Wt = wt1; K = 768; N = 3072;
      k0 = (r%24)*32; n0 = (r/24)*32;
    } else {
      int r = id - 4608;
      W = W2; Wt = wt2; K = 3072; N = 768;
      k0 = (r/24)*32; n0 = (r%24)*32;
    }
    int tx = t & 31, ty = t >> 5;
    #pragma unroll
    for (int p=0;p<4;p++)
      tl[ty+8*p][tx] = W[(size_t)(k0+ty+8*p)*N + (n0+tx)];
    __syncthreads();
    #pragma unroll
    for (int p=0;p<4;p++){
      int n = ty+8*p;
      Wt[(size_t)(n0+n)*K + (k0+tx)] = f2bf(tl[tx][n]);
    }
    return;
  }

  // LN1 (f32 in -> bf16 out)
  int row = id - 6912;
  const float* xr = x + (size_t)row*768;
  float v0 = xr[t], v1 = xr[t+256], v2 = xr[t+512];
  float s = v0+v1+v2, s2 = v0*v0+v1*v1+v2*v2;
  #pragma unroll
  for (int m=1;m<64;m<<=1){ s += __shfl_xor(s,m); s2 += __shfl_xor(s2,m); }
  int w = t>>6;
  if ((t&63)==0){ ls[w]=s; ls2[w]=s2; }
  __syncthreads();
  s = ls[0]+ls[1]+ls[2]+ls[3]; s2 = ls2[0]+ls2[1]+ls2[2]+ls2[3];
  float mu = s*(1.0f/768.0f);
  float rstd = rsqrtf(s2*(1.0f/768.0f) - mu*mu + 1e-5f);
  u16* orow = out + (size_t)row*768;
  orow[t]     = f2bf((v0-mu)*rstd*g[t]     + bta[t]);
  orow[t+256] = f2bf((v1-mu)*rstd*g[t+256] + bta[t+256]);
  orow[t+512] = f2bf((v2-mu)*rstd*g[t+512] + bta[t+512]);
}

// ---------- layernorm: in (f32 or bf16) [rows][768] -> bf16 out ----------
template<bool INBF16>
__global__ __launch_bounds__(256) void ln_kernel(const void* __restrict__ xin,
                                                 const float* __restrict__ g,
                                                 const float* __restrict__ bta,
                                                 u16* __restrict__ out){
  int row = blockIdx.x, t = threadIdx.x;
  float v0, v1, v2;
  if (INBF16){
    const u16* xr = (const u16*)xin + (size_t)row*768;
    v0 = bf2f(xr[t]); v1 = bf2f(xr[t+256]); v2 = bf2f(xr[t+512]);
  } else {
    const float* xr = (const float*)xin + (size_t)row*768;
    v0 = xr[t]; v1 = xr[t+256]; v2 = xr[t+512];
  }
  float s = v0+v1+v2, s2 = v0*v0+v1*v1+v2*v2;
  #pragma unroll
  for (int m=1;m<64;m<<=1){ s += __shfl_xor(s,m); s2 += __shfl_xor(s2,m); }
  __shared__ float ls[4], ls2[4];
  int w = t>>6;
  if ((t&63)==0){ ls[w]=s; ls2[w]=s2; }
  __syncthreads();
  s = ls[0]+ls[1]+ls[2]+ls[3]; s2 = ls2[0]+ls2[1]+ls2[2]+ls2[3];
  float mu = s*(1.0f/768.0f);
  float rstd = rsqrtf(s2*(1.0f/768.0f) - mu*mu + 1e-5f);
  u16* orow = out + (size_t)row*768;
  orow[t]     = f2bf((v0-mu)*rstd*g[t]     + bta[t]);
  orow[t+256] = f2bf((v1-mu)*rstd*g[t+256] + bta[t+256]);
  orow[t+512] = f2bf((v2-mu)*rstd*g[t+512] + bta[t+512]);
}

// ---------- GEMM: BK=64, granule-swizzled LDS, templated tile-M ----------
// VPERM: z==2 (V) output written directly to vtb in per-head transposed
// k-interleaved layout (pairs (k,k+16) adjacent). RESBF16: residual as bf16.
// NOTE (r16): XCD-aware A-major block remap REGRESSED ~4-5us -- keep plain.
template<bool GELU, bool RES, bool OUTBF16, int BM, bool VPERM=false, bool RESBF16=false>
__global__ __launch_bounds__(256) void gemm_kernel(
    const u16* __restrict__ A, const u16* __restrict__ Bt0, size_t btStride,
    const float* __restrict__ bias0, const float* __restrict__ bias1, const float* __restrict__ bias2,
    const void* __restrict__ res, void* __restrict__ out0, size_t outStride,
    int M, int N, int K, float qscale, u32* __restrict__ vtb = nullptr)
{
  constexpr int AM = BM/32;            // M-frags per wave (4 or 2)
  __shared__ u16 As[BM*64];
  __shared__ u16 Bs[128*64];
  const int t = threadIdx.x, lane = t & 63, w = t >> 6;
  const int lj = lane & 15, g = lane >> 4;
  const int wm = w >> 1, wn = w & 1;
  const int z = blockIdx.z;
  const u16* Bt = Bt0 + (size_t)z * btStride;
  const float* bias = (z==0) ? bias0 : (z==1 ? bias1 : bias2);
  const u16* Arow = A  + (size_t)blockIdx.x * BM * K;
  const u16* Brow = Bt + (size_t)blockIdx.y * 128 * K;

  f32x4 acc[AM][4];
  #pragma unroll
  for (int a=0;a<AM;a++)
    #pragma unroll
    for (int b=0;b<4;b++){ f32x4 zz = {0.f,0.f,0.f,0.f}; acc[a][b] = zz; }

  for (int kk=0; kk<K; kk+=64){
    #pragma unroll
    for (int cc=0;cc<BM/32;cc++){
      int c = cc*256 + t;
      int row = c>>3, gp = c&7;
      gload16(Arow + (size_t)row*K + kk + ((gp ^ (row&7))<<3),
              (void*)(As + (size_t)(cc*256 + w*64)*8));
    }
    #pragma unroll
    for (int cc=0;cc<4;cc++){
      int c = cc*256 + t;
      int row = c>>3, gp = c&7;
      gload16(Brow + (size_t)row*K + kk + ((gp ^ (row&7))<<3),
              (void*)(Bs + (size_t)(cc*256 + w*64)*8));
    }
    __syncthreads();                    // drains vmcnt: DMA writes visible
    #pragma unroll
    for (int ks=0;ks<2;ks++){
      s16x8 af[AM], bfr[4];
      #pragma unroll
      for (int mt=0;mt<AM;mt++){
        int row = wm*(BM/2)+mt*16+lj;
        af[mt]  = *(const s16x8*)&As[(size_t)row*64 + (((ks*4+g) ^ (lj&7))<<3)];
      }
      #pragma unroll
      for (int nt=0;nt<4;nt++){
        int row = wn*64+nt*16+lj;
        bfr[nt] = *(const s16x8*)&Bs[(size_t)row*64 + (((ks*4+g) ^ (lj&7))<<3)];
      }
      #pragma unroll
      for (int mt=0;mt<AM;mt++)
        #pragma unroll
        for (int nt=0;nt<4;nt++)
          acc[mt][nt] = __builtin_amdgcn_mfma_f32_16x16x32_bf16(af[mt], bfr[nt], acc[mt][nt], 0,0,0);
    }
    __syncthreads();                    // readers done before next stage
  }

  const size_t gr0 = (size_t)blockIdx.x*BM + wm*(BM/2);
  const int gc0 = blockIdx.y*128 + wn*64;

  if (VPERM && z == 2){
    // direct V write: vtb[bh][d][4096 k-perm], one dword per (mt-pair, nt, r)
    const int b_ = (int)(gr0 >> 12);
    const int kt = (int)((gr0 & 4095) >> 6);   // constant per (block,wm)
    #pragma unroll
    for (int mt2=0; mt2<AM; mt2+=2){
      const u32 gnq = 4*(mt2>>1) + g;          // granule index within 64-k tile
      #pragma unroll
      for (int nt=0;nt<4;nt++){
        int gc = gc0 + nt*16 + lj;
        int hh = gc>>6, dd = gc&63;
        float bv = bias[gc];
        size_t base = ((size_t)(b_*12+hh)*64 + dd)*2048 + (size_t)kt*32 + gnq*4;
        #pragma unroll
        for (int r=0;r<4;r++){
          float ve = acc[mt2][nt][r]   + bv;
          float vo = acc[mt2+1][nt][r] + bv;
          vtb[base + r] = cvtpk_bf16(ve, vo);
        }
      }
    }
    return;
  }

  float* outF = (float*)out0; u16* outB = (u16*)out0;
  if (OUTBF16) outB += (size_t)z*outStride; else outF += (size_t)z*outStride;
  #pragma unroll
  for (int mt=0;mt<AM;mt++)
    #pragma unroll
    for (int nt=0;nt<4;nt++){
      int gc = gc0 + nt*16 + lj;
      float bv = bias[gc];
      #pragma unroll
      for (int r=0;r<4;r++){
        size_t gr = gr0 + mt*16 + g*4 + r;
        float val = acc[mt][nt][r] + bv;
        if (z==0) val *= qscale;
        if (RES){
          if (RESBF16) val += bf2f(((const u16*)res)[gr*(size_t)N + gc]);
          else         val += ((const float*)res)[gr*(size_t)N + gc];
        }
        if (GELU) val = gelu_tanh(val);
        if (OUTBF16) outB[gr*(size_t)N + gc] = f2bf(val);
        else         outF[gr*(size_t)N + gc] = val;
      }
    }
}

// ---------- attention (proven structure + XCD-aware bh-cluster remap) ----------
// Block = (b,h,q-quarter,pair pp): iw=pp then 15-pp -> 17 units, 3 blocks/CU.
// XCD remap bx=(id%8)*96+id/8: each XCD owns 3 whole (b,h) slices; their K+V
// (3MB) fit the 4MB per-XCD L2 -> FETCH_SIZE 115MB->23.5MB measured (r16).
// One 32KB KV buffer: K -> QK -> stage V under softmax -> PV raw -> cacc+=rs*pacc.
// Swapped QK (S^T lane-local), in-register P via cvtpk, deferred normalization.
// launch_bounds(256,3): (256,4) forces 64-VGPR target and spills sacc (r5,r9).
// r18: K-prefetch-to-registers (+32 VGPR) spilled to scratch (WRITE 142MB) --
// this kernel has no VGPR headroom at 84; do not add register state.
__global__ __launch_bounds__(256,3) void attn_kernel(
    const u16* __restrict__ qb, const u16* __restrict__ kb,
    const u16* __restrict__ vtb, u16* __restrict__ ctx)
{
  __shared__ u16 KV[256*64];       // K: [krow 256][8 gran, ^=(krow&7)] ; V: [d 64][32 gran, ^=(d&15)]
  const int t = threadIdx.x, lane = t & 63, w = t >> 6;
  const int lj = lane & 15, g = lane >> 4;
  const int bx = (blockIdx.x & 7) * 96 + (blockIdx.x >> 3);   // XCD-cluster by bh
  const int pp = bx & 7, qq = (bx >> 3) & 3, bh = bx >> 5;
  const int h = bh % 12, b = bh / 12;
  const size_t seqbase = (size_t)b * 4096;
  const int hoff = h * 64;

  #pragma unroll
  for (int f=0; f<2; f++){
    const int iw = f ? (15 - pp) : pp;
    const int qrow0 = iw*256 + qq*64 + w*16;

    s16x8 qa[2];
    #pragma unroll
    for (int ks=0;ks<2;ks++)
      qa[ks] = *(const s16x8*)(qb + (seqbase + qrow0 + lj)*768 + hoff + ks*32 + g*8);

    f32x4 cacc[4];
    #pragma unroll
    for (int dt=0;dt<4;dt++){ f32x4 zz = {0.f,0.f,0.f,0.f}; cacc[dt] = zz; }

    for (int jw=0; jw<=iw; jw++){
      const u16* kwin = kb + (seqbase + jw*256)*768 + hoff;
      const u16* vtwin = vtb + (size_t)bh*64*4096 + jw*256;

      __syncthreads();                       // prev PV reads done before K overwrite
      #pragma unroll
      for (int cc=0;cc<8;cc++){
        int c = cc*256 + t;
        int krow = c>>3, vp = c&7;
        gload16(kwin + (size_t)krow*768 + ((vp ^ (krow&7))<<3),
                (void*)(KV + (size_t)(cc*256 + w*64)*8));
      }
      __syncthreads();                       // K visible

      // swapped QK: sacc[kt][r] = S^T[k = kt*16+4g+r][q = lj]
      f32x4 sacc[16];
      #pragma unroll
      for (int kt=0;kt<16;kt++){ f32x4 zz = {0.f,0.f,0.f,0.f}; sacc[kt] = zz; }
      __builtin_amdgcn_s_setprio(1);
      #pragma unroll
      for (int kt=0;kt<16;kt++){
        int kl = kt*16 + lj;
        #pragma unroll
        for (int ks=0;ks<2;ks++){
          s16x8 kf = *(const s16x8*)&KV[ (size_t)kl*64 + (((4*ks+g) ^ (kl&7))<<3) ];
          sacc[kt] = __builtin_amdgcn_mfma_f32_16x16x32_bf16(kf, qa[ks], sacc[kt], 0,0,0);
        }
      }
      __builtin_amdgcn_s_setprio(0);
      __syncthreads();                       // QK reads of KV done

      // stage V (perm layout) -- latency hides under softmax below
      #pragma unroll
      for (int cc=0;cc<8;cc++){
        int c = cc*256 + t;
        int d = c>>5, cp = c&31;
        gload16(vtwin + (size_t)d*4096 + ((cp ^ (d&15))<<3),
                (void*)(KV + (size_t)(cc*256 + w*64)*8));
      }

      // softmax over 256 k for q=lj: in-lane exp2 + 2 cross-group shuffles
      float sm = 0.f;
      #pragma unroll
      for (int kt=0;kt<16;kt++)
        #pragma unroll
        for (int r=0;r<4;r++){
          float pv = fexp2(sacc[kt][r]);
          sacc[kt][r] = pv; sm += pv;
        }
      sm += __shfl_xor(sm, 16);
      sm += __shfl_xor(sm, 32);
      float rs = frcp(sm);

      __syncthreads();                       // V staged visible (drains vmcnt)

      // PV on RAW exp values into pacc; normalize once per window at the end
      f32x4 pacc[4];
      #pragma unroll
      for (int dt=0;dt<4;dt++){ f32x4 zz = {0.f,0.f,0.f,0.f}; pacc[dt] = zz; }
      #pragma unroll
      for (int ks=0;ks<8;ks++){
        u32x4 pw;
        #pragma unroll
        for (int r=0;r<4;r++)
          pw[r] = cvtpk_bf16(sacc[2*ks][r], sacc[2*ks+1][r]);
        s16x8 pa = __builtin_bit_cast(s16x8, pw);
        __builtin_amdgcn_s_setprio(1);
        #pragma unroll
        for (int dt=0;dt<4;dt++){
          int d = dt*16 + lj;
          s16x8 vf = *(const s16x8*)&KV[ (size_t)d*256 + (((4*ks+g) ^ (d&15))<<3) ];
          pacc[dt] = __builtin_amdgcn_mfma_f32_16x16x32_bf16(pa, vf, pacc[dt], 0,0,0);
        }
        __builtin_amdgcn_s_setprio(0);
      }
      #pragma unroll
      for (int dt=0;dt<4;dt++)
        #pragma unroll
        for (int r=0;r<4;r++)
          cacc[dt][r] += rs * pacc[dt][r];
    }

    #pragma unroll
    for (int dt=0;dt<4;dt++)
      #pragma unroll
      for (int r=0;r<4;r++){
        int qrow = qrow0 + g*4 + r;
        ctx[ (seqbase + qrow)*768 + hoff + dt*16 + lj ] = f2bf(cacc[dt][r]);
      }
  }
}

extern "C" void kernel_launch(void* const* d_in, const int* in_sizes, int n_in,
                              void* d_out, int out_size, void* d_ws, size_t ws_size,
                              hipStream_t stream)
{
  const float* x    = (const float*)d_in[0];
  const float* Wq   = (const float*)d_in[1];
  const float* bq   = (const float*)d_in[2];
  const float* Wk   = (const float*)d_in[3];
  const float* bk   = (const float*)d_in[4];
  const float* Wv   = (const float*)d_in[5];
  const float* bv   = (const float*)d_in[6];
  const float* Wo   = (const float*)d_in[7];
  const float* bo   = (const float*)d_in[8];
  const float* ln1g = (const float*)d_in[9];
  const float* ln1b = (const float*)d_in[10];
  const float* W1   = (const float*)d_in[11];
  const float* b1   = (const float*)d_in[12];
  const float* W2   = (const float*)d_in[13];
  const float* b2   = (const float*)d_in[14];
  const float* ln2g = (const float*)d_in[15];
  const float* ln2b = (const float*)d_in[16];

  char* ws = (char*)d_ws;
  constexpr size_t SZ_W768  = (size_t)768*768*2;
  constexpr size_t SZ_W3072 = (size_t)768*3072*2;
  constexpr size_t SZ_HB    = (size_t)8192*768*2;
  u16* wtq = (u16*)(ws);
  u16* wtk = (u16*)(ws + SZ_W768);
  u16* wtv = (u16*)(ws + 2*SZ_W768);
  u16* wto = (u16*)(ws + 3*SZ_W768);
  u16* wt1 = (u16*)(ws + 4*SZ_W768);
  u16* wt2 = (u16*)(ws + 4*SZ_W768 + SZ_W3072);
  char* p0 = ws + 4*SZ_W768 + 2*SZ_W3072;
  u16*   hbuf  = (u16*)p0;              // LN1/LN2 out (bf16)
  u16*   qbuf  = (u16*)(p0 + SZ_HB);
  u16*   kbuf  = (u16*)(p0 + 2*SZ_HB);
  u16*   vtbuf = (u16*)(p0 + 3*SZ_HB);  // V written DIRECTLY in perm layout by QKV
  u16*   cbuf  = (u16*)(p0 + 4*SZ_HB);
  u16*   x1    = (u16*)(p0 + 5*SZ_HB);  // attention residual stream, bf16
  u16*   ffa   = qbuf;                  // FF activations span slots 1-4
  float* outp  = (float*)d_out;

  // prep: all weight transposes + LN1 in ONE launch (15104 blocks)
  prep_kernel<<<15104, 256, 0, stream>>>(
      Wq, Wk, Wv, Wo, W1, W2, wtq, wtk, wtv, wto, wt1, wt2,
      x, ln1g, ln1b, hbuf);

  // QKV (z-fused, BM=128); Q pre-scaled by (1/8)*log2(e); V -> vtbuf direct
  gemm_kernel<false,false,true,128,true><<<dim3(64,6,3), 256, 0, stream>>>(
      hbuf, wtq, (size_t)768*768, bq, bk, bv, nullptr, qbuf, (size_t)8192*768,
      8192, 768, 768, 0.180336880111f, (u32*)vtbuf);
  // attention
  attn_kernel<<<768, 256, 0, stream>>>(qbuf, kbuf, vtbuf, cbuf);
  // Wo + residual(x, f32) -> x1 (bf16); BM=64 -> 768 blocks, 3/CU balanced
  gemm_kernel<false,true,true,64><<<dim3(128,6,1), 256, 0, stream>>>(
      cbuf, wto, 0, bo, bo, bo, x, x1, 0, 8192, 768, 768, 1.0f);
  // LN2 (bf16 in) -> hbuf (bf16)
  ln_kernel<true><<<8192, 256, 0, stream>>>(x1, ln2g, ln2b, hbuf);
  // FF1 + tanh-gelu -> ffa (bf16)
  gemm_kernel<true,false,true,128><<<dim3(64,24,1), 256, 0, stream>>>(
      hbuf, wt1, 0, b1, b1, b1, nullptr, ffa, 0, 8192, 3072, 768, 1.0f);
  // FF2 + residual(x1, bf16) -> out (f32); BM=64 -> 768 blocks, 3/CU
  gemm_kernel<false,true,false,64,false,true><<<dim3(128,6,1), 256, 0, stream>>>(
      ffa, wt2, 0, b2, b2, b2, x1, outp, 0, 8192, 768, 3072, 1.0f);
}